// Round 8
// baseline (329.500 us; speedup 1.0000x reference)
//
#include <hip/hip_runtime.h>
#include <hip/hip_bf16.h>
#include <math.h>

#define NV 50000
#define NE 600000
#define NM 100000
#define KIN 256
#define HCC 256
#define NHH 8

// chunked LDS histogram geometry
#define NCH 96                 // chunks (3x more than r7: 25 latency-iters/block, not 73)
#define CHUNK 6250             // NE / NCH
#define KRANGE 25000           // keys per LDS pass (u16-packed: 12500 u32 = 50KB)
#define NPASS 6                // passes 0-3: e-side (4x25K=100K), 4-5: v-side (2x25K=50K)
#define HIST_B (NCH * NPASS)   // 576
#define CSCAN_B 74             // ceil((NM/2 + NV/2)/1024)

// parallel scan geometry: 4096 elements per block (1024 threads x int4)
#define SCAN_NB0 25   // ceil((NM+1)/4096)
#define SCAN_NB1 13   // ceil((NV+1)/4096)

#define CNT_B 2344    // ceil(NE/256) incidence blocks (fill kernel)
#define GEMM_RG 784   // row-groups launched (782 real + 2 spare for the 8-row remap)
#define GEMM_B (GEMM_RG * 4)

typedef unsigned int u32;
typedef unsigned short u16;
typedef _Float16 f16;
typedef _Float16 v8h __attribute__((ext_vector_type(8)));
typedef _Float16 v4h __attribute__((ext_vector_type(4)));
typedef float v4f __attribute__((ext_vector_type(4)));
typedef float v8f __attribute__((ext_vector_type(8)));

// ---- fused: chunked LDS histogram+rank blocks || fp16 MFMA GEMM blocks ----
// Shared-LDS union: hist uses 50KB (u16-packed pairs), gemm carves sA/sB (18.4KB)
// from the same block -> 3 blocks/CU either way. Hist blocks (576, latency-bound)
// dispatch first; the 3136 gemm blocks fill the machine underneath them.
// Global atomics stay eliminated (rounds 3-5: fixed ~12.5 G/s shared pipe).
__global__ __launch_bounds__(256) void k_hist_gemm(const int* __restrict__ vertex,
                                                   const int* __restrict__ edges,
                                                   u16* __restrict__ r_e,
                                                   u16* __restrict__ r_v,
                                                   u16* __restrict__ Ce,
                                                   u16* __restrict__ Cv,
                                                   const float* __restrict__ X,
                                                   const float* __restrict__ W,
                                                   f16* __restrict__ X0) {
    __shared__ __align__(16) u32 smem[KRANGE / 2];   // 50KB, unioned
    const int bid = blockIdx.x;
    const int t = threadIdx.x;
    if (bid < HIST_B) {
        u32* hist = smem;
        const int pass = bid / NCH;          // 0..5
        const int chunk = bid % NCH;
        const bool eside = pass < 4;
        const int kbase = (eside ? pass : pass - 4) * KRANGE;
        const int* keys = eside ? edges : vertex;
        u16* rout = eside ? r_e : r_v;
        u16* crow = eside ? (Ce + (size_t)chunk * NM) : (Cv + (size_t)chunk * NV);

        uint4* h4 = (uint4*)hist;
        for (int j = t; j < KRANGE / 8; j += 256) h4[j] = make_uint4(0u, 0u, 0u, 0u);
        __syncthreads();

        const int i0 = chunk * CHUNK;
        for (int i = i0 + t; i < i0 + CHUNK; i += 256) {
            int k = keys[i] - kbase;
            if ((u32)k < (u32)KRANGE) {
                int sh = (k & 1) << 4;
                u32 old = atomicAdd(&hist[k >> 1], 1u << sh);
                rout[i] = (u16)(old >> sh);
            }
        }
        __syncthreads();

        uint4* d4 = (uint4*)(crow + kbase);  // 16B-aligned: strides & kbase*2 %16==0
        for (int j = t; j < KRANGE / 8; j += 256) d4[j] = h4[j];
        return;
    }
    // ---- GEMM blocks: X0 = f16(X @ W), 64x64 tiles ----
    // XCD remap g&7==rg&7 (HIST_B%8==0 preserves it) -> X fetched once (r3: 102->28MB)
    typedef f16 (*tile_t)[72];
    tile_t sA = (tile_t)smem;
    tile_t sB = (tile_t)((char*)smem + 64 * 72 * 2);
    const int g = bid - HIST_B;
    const int rg = (g >> 5) * 8 + (g & 7);     // row-group
    const int cg = (g >> 3) & 3;               // column-group
    if (rg >= (NV + 63) / 64) return;
    const int r0 = rg * 64;
    const int c0 = cg * 64;
    const int wave = t >> 6;
    const int lane = t & 63;
    const int quad = lane >> 4;
    const int l16 = lane & 15;
    const int wr = wave & 1;
    const int wc = wave >> 1;

    v4f acc[2][2] = {{{0.f,0.f,0.f,0.f},{0.f,0.f,0.f,0.f}},
                     {{0.f,0.f,0.f,0.f},{0.f,0.f,0.f,0.f}}};

    for (int kc = 0; kc < KIN; kc += 64) {
        __syncthreads();
        #pragma unroll
        for (int i = 0; i < 4; ++i) {
            int lin = i * 256 + t;
            int row = lin >> 4;
            int k = (lin & 15) * 4;
            int gr = r0 + row;
            float4 x = make_float4(0.f, 0.f, 0.f, 0.f);
            if (gr < NV) x = *(const float4*)(X + (size_t)gr * KIN + kc + k);
            v4h hv = { (f16)x.x, (f16)x.y, (f16)x.z, (f16)x.w };
            *(v4h*)&sA[row][k] = hv;
        }
        #pragma unroll
        for (int i = 0; i < 4; ++i) {
            int lin = i * 256 + t;
            int k = lin >> 4;
            int n = (lin & 15) * 4;
            float4 b = *(const float4*)(W + (size_t)(kc + k) * HCC + c0 + n);
            sB[n + 0][k] = (f16)b.x;
            sB[n + 1][k] = (f16)b.y;
            sB[n + 2][k] = (f16)b.z;
            sB[n + 3][k] = (f16)b.w;
        }
        __syncthreads();
        #pragma unroll
        for (int ks = 0; ks < 2; ++ks) {
            const int kb = ks * 32 + quad * 8;
            v8h a[2], b[2];
            #pragma unroll
            for (int rf = 0; rf < 2; ++rf)
                a[rf] = *(const v8h*)&sA[wr * 32 + rf * 16 + l16][kb];
            #pragma unroll
            for (int cf = 0; cf < 2; ++cf)
                b[cf] = *(const v8h*)&sB[wc * 32 + cf * 16 + l16][kb];
            #pragma unroll
            for (int rf = 0; rf < 2; ++rf)
                #pragma unroll
                for (int cf = 0; cf < 2; ++cf)
                    acc[rf][cf] = __builtin_amdgcn_mfma_f32_16x16x32_f16(a[rf], b[cf], acc[rf][cf], 0, 0, 0);
        }
    }
    #pragma unroll
    for (int rf = 0; rf < 2; ++rf)
        #pragma unroll
        for (int cf = 0; cf < 2; ++cf)
            #pragma unroll
            for (int r = 0; r < 4; ++r) {
                int grow = r0 + wr * 32 + rf * 16 + quad * 4 + r;
                if (grow < NV)
                    X0[(size_t)grow * HCC + c0 + wc * 32 + cf * 16 + l16] = (f16)acc[rf][cf][r];
            }
}

// ---- column scan over chunks: C[c][k] -> exclusive prefix over c; totals out ----
// Packed-u32 arithmetic on u16 pairs (no carry: per-key totals <= ~60).
__global__ __launch_bounds__(1024) void k_cscan(u16* __restrict__ Ce,
                                                u16* __restrict__ Cv,
                                                int* __restrict__ e_start,
                                                int* __restrict__ v_start) {
    int tid = blockIdx.x * 1024 + threadIdx.x;
    u32* mat;
    int* outp;
    int col, ncol;
    if (tid < NM / 2)               { mat = (u32*)Ce; outp = e_start; col = tid;          ncol = NM / 2; }
    else if (tid < NM / 2 + NV / 2) { mat = (u32*)Cv; outp = v_start; col = tid - NM / 2; ncol = NV / 2; }
    else return;
    u32 s = 0;
    u32* p = mat + col;
    for (int c = 0; c < NCH; ++c) {
        u32 o = *p;
        *p = s;
        s += o;
        p += ncol;
    }
    outp[2 * col + 1] = (int)(s & 0xffffu);
    outp[2 * col + 2] = (int)(s >> 16);
}

// ---------------- parallel scan pass 1: per-block inclusive scan + block sums ------
__global__ __launch_bounds__(1024) void k_scan_blk(int* __restrict__ a0,
                                                   int* __restrict__ a1,
                                                   int* __restrict__ bsum) {
    const int b = blockIdx.x;
    int* a;
    int n, base;
    if (b < SCAN_NB0) { a = a0; n = NM + 1; base = b * 4096; }
    else              { a = a1; n = NV + 1; base = (b - SCAN_NB0) * 4096; }
    const int t = threadIdx.x;
    const int lane = t & 63, w = t >> 6;
    const int i = base + t * 4;
    int4 v = make_int4(0, 0, 0, 0);
    if (i + 3 < n) v = *(const int4*)(a + i);
    else if (i < n) {
        v.x = a[i];
        if (i + 1 < n) v.y = a[i + 1];
        if (i + 2 < n) v.z = a[i + 2];
    }
    v.y += v.x; v.z += v.y; v.w += v.z;
    int s = v.w;
    #pragma unroll
    for (int d = 1; d < 64; d <<= 1) {
        int x = __shfl_up(s, d, 64);
        if (lane >= d) s += x;
    }
    __shared__ int partials[16];
    __shared__ int woff[16];
    if (lane == 63) partials[w] = s;
    __syncthreads();
    if (t < 16) {
        int p = partials[t];
        int ps = p;
        #pragma unroll
        for (int d = 1; d < 16; d <<= 1) {
            int x = __shfl_up(ps, d, 64);
            if (t >= d) ps += x;
        }
        woff[t] = ps - p;
        if (t == 15) bsum[b] = ps;
    }
    __syncthreads();
    const int add = (s - v.w) + woff[w];
    v.x += add; v.y += add; v.z += add; v.w += add;
    if (i + 3 < n) *(int4*)(a + i) = v;
    else if (i < n) {
        a[i] = v.x;
        if (i + 1 < n) a[i + 1] = v.y;
        if (i + 2 < n) a[i + 2] = v.z;
    }
}

// ---------------- parallel scan pass 2: add block offsets ----------------
__global__ __launch_bounds__(1024) void k_scan_add(int* __restrict__ a0,
                                                   int* __restrict__ a1,
                                                   const int* __restrict__ bsum) {
    const int b = blockIdx.x;
    int* a;
    int n, bs0, blocal;
    if (b < SCAN_NB0) { a = a0; n = NM + 1; bs0 = 0;        blocal = b; }
    else              { a = a1; n = NV + 1; bs0 = SCAN_NB0; blocal = b - SCAN_NB0; }
    const int t = threadIdx.x;
    const int lane = t & 63;
    int x = (lane < blocal) ? bsum[bs0 + lane] : 0;
    #pragma unroll
    for (int d = 1; d < 64; d <<= 1) x += __shfl_xor(x, d, 64);
    const int off = x;
    const int i = blocal * 4096 + t * 4;
    if (i + 3 < n) {
        int4 v = *(const int4*)(a + i);
        v.x += off; v.y += off; v.z += off; v.w += off;
        *(int4*)(a + i) = v;
    } else if (i < n) {
        a[i] += off;
        if (i + 1 < n) a[i + 1] += off;
        if (i + 2 < n) a[i + 2] += off;
    }
}

// ---------------- merged CSR fill: both sides, one pass, atomic-free ----------------
// pos = segment start + chunk offset (cscan) + rank-within-(chunk,segment).
// Shares the vertex/edges/rank loads between the two scatters.
__global__ __launch_bounds__(256) void k_fill2(const int* __restrict__ vertex,
                                               const int* __restrict__ edges,
                                               const u16* __restrict__ r_e,
                                               const u16* __restrict__ r_v,
                                               const int* __restrict__ e_start,
                                               const int* __restrict__ v_start,
                                               const u16* __restrict__ Ce,
                                               const u16* __restrict__ Cv,
                                               int* __restrict__ e_list,
                                               int* __restrict__ v_list) {
    int i = blockIdx.x * 256 + threadIdx.x;
    if (i >= NE) return;
    int v = vertex[i], m = edges[i];
    int chunk = i / CHUNK;
    int pe = e_start[m] + (int)Ce[(size_t)chunk * NM + m] + (int)r_e[i];
    e_list[pe] = v;
    int pv = v_start[v] + (int)Cv[(size_t)chunk * NV + v] + (int)r_v[i];
    v_list[pv] = m;
}

// ---------------- per-hyperedge gather: mean of member X0 rows + alpha_e ----------------
// one wave per hyperedge; 16B/lane (v8h): half-wave = even/odd member, lane owns
// 8 channels; halves merged with one shfl_xor(32) per channel at the end.
__global__ __launch_bounds__(256) void k_egather(const int* __restrict__ e_start,
                                                 const int* __restrict__ e_list,
                                                 const f16* __restrict__ X0,
                                                 const float* __restrict__ att,
                                                 f16* __restrict__ Xe,
                                                 float* __restrict__ alpha_e) {
    int m = blockIdx.x * 4 + (threadIdx.x >> 6);
    int lane = threadIdx.x & 63;
    int half = lane >> 5;
    int l32 = lane & 31;
    int c8 = l32 * 8;
    int s0 = e_start[m], s1 = e_start[m + 1];
    v8f acc = {0.f,0.f,0.f,0.f,0.f,0.f,0.f,0.f};
    int i = s0 + half;
    for (; i + 2 < s1; i += 4) {
        int v0 = e_list[i], v1 = e_list[i + 2];
        v8h x0 = *(const v8h*)(X0 + (size_t)v0 * HCC + c8);
        v8h x1 = *(const v8h*)(X0 + (size_t)v1 * HCC + c8);
        #pragma unroll
        for (int j = 0; j < 8; ++j) acc[j] += (float)x0[j] + (float)x1[j];
    }
    if (i < s1) {
        int v0 = e_list[i];
        v8h x0 = *(const v8h*)(X0 + (size_t)v0 * HCC + c8);
        #pragma unroll
        for (int j = 0; j < 8; ++j) acc[j] += (float)x0[j];
    }
    #pragma unroll
    for (int j = 0; j < 8; ++j) acc[j] += __shfl_xor(acc[j], 32, 64);
    float inv = 1.0f / fmaxf((float)(s1 - s0), 1.0f);
    #pragma unroll
    for (int j = 0; j < 8; ++j) acc[j] *= inv;
    if (half == 0) {
        v8h xv;
        #pragma unroll
        for (int j = 0; j < 8; ++j) xv[j] = (f16)acc[j];
        *(v8h*)(Xe + (size_t)m * HCC + c8) = xv;
    }
    float4 a0 = *(const float4*)(att + c8);
    float4 a1 = *(const float4*)(att + c8 + 4);
    float p = acc[0]*a0.x + acc[1]*a0.y + acc[2]*a0.z + acc[3]*a0.w
            + acc[4]*a1.x + acc[5]*a1.y + acc[6]*a1.z + acc[7]*a1.w;
    p += __shfl_xor(p, 1, 64);
    p += __shfl_xor(p, 2, 64);
    if (half == 0 && (l32 & 3) == 0) alpha_e[m * NHH + (l32 >> 2)] = p;
}

// ---------------- per-vertex gather: softmax (no max shift; |alpha|<~2) + GELU ----------
// 16B/lane v8h Xe loads; half-wave = even/odd incident edge; merge via shfl_xor(32).
__global__ __launch_bounds__(256) void k_vgather(const int* __restrict__ v_start,
                                                 const int* __restrict__ v_list,
                                                 const f16* __restrict__ Xe,
                                                 const float* __restrict__ alpha_e,
                                                 float* __restrict__ out) {
    int v = blockIdx.x * 4 + (threadIdx.x >> 6);
    int lane = threadIdx.x & 63;
    int half = lane >> 5;
    int l32 = lane & 31;
    int h = l32 >> 2;
    int c8 = l32 * 8;
    int s0 = v_start[v], s1 = v_start[v + 1];
    v8f acc = {0.f,0.f,0.f,0.f,0.f,0.f,0.f,0.f};
    float se = 0.f;
    int i = s0 + half;
    for (; i + 2 < s1; i += 4) {
        int m0 = v_list[i], m1 = v_list[i + 2];
        float a0 = alpha_e[m0 * NHH + h];
        float a1 = alpha_e[m1 * NHH + h];
        v8h x0 = *(const v8h*)(Xe + (size_t)m0 * HCC + c8);
        v8h x1 = *(const v8h*)(Xe + (size_t)m1 * HCC + c8);
        a0 = (a0 >= 0.f) ? a0 : 0.2f * a0;
        a1 = (a1 >= 0.f) ? a1 : 0.2f * a1;
        float e0 = __expf(a0);
        float e1 = __expf(a1);
        #pragma unroll
        for (int j = 0; j < 8; ++j) acc[j] += e0 * (float)x0[j] + e1 * (float)x1[j];
        se += e0 + e1;
    }
    if (i < s1) {
        int m0 = v_list[i];
        float a0 = alpha_e[m0 * NHH + h];
        v8h x0 = *(const v8h*)(Xe + (size_t)m0 * HCC + c8);
        a0 = (a0 >= 0.f) ? a0 : 0.2f * a0;
        float e0 = __expf(a0);
        #pragma unroll
        for (int j = 0; j < 8; ++j) acc[j] += e0 * (float)x0[j];
        se += e0;
    }
    #pragma unroll
    for (int j = 0; j < 8; ++j) acc[j] += __shfl_xor(acc[j], 32, 64);
    se += __shfl_xor(se, 32, 64);
    if (half) return;
    float inv = 1.0f / (se + 1e-16f);
    float4 o0, o1;
    float xx;
    xx = acc[0] * inv; o0.x = 0.5f * xx * (1.f + erff(xx * 0.70710678118f));
    xx = acc[1] * inv; o0.y = 0.5f * xx * (1.f + erff(xx * 0.70710678118f));
    xx = acc[2] * inv; o0.z = 0.5f * xx * (1.f + erff(xx * 0.70710678118f));
    xx = acc[3] * inv; o0.w = 0.5f * xx * (1.f + erff(xx * 0.70710678118f));
    xx = acc[4] * inv; o1.x = 0.5f * xx * (1.f + erff(xx * 0.70710678118f));
    xx = acc[5] * inv; o1.y = 0.5f * xx * (1.f + erff(xx * 0.70710678118f));
    xx = acc[6] * inv; o1.z = 0.5f * xx * (1.f + erff(xx * 0.70710678118f));
    xx = acc[7] * inv; o1.w = 0.5f * xx * (1.f + erff(xx * 0.70710678118f));
    *(float4*)(out + (size_t)v * HCC + c8) = o0;
    *(float4*)(out + (size_t)v * HCC + c8 + 4) = o1;
}

extern "C" void kernel_launch(void* const* d_in, const int* in_sizes, int n_in,
                              void* d_out, int out_size, void* d_ws, size_t ws_size,
                              hipStream_t stream) {
    const float* X = (const float*)d_in[0];    // [NV, 256] fp32
    const float* W = (const float*)d_in[1];    // [256, 256] fp32
    const float* att = (const float*)d_in[2];  // [256] fp32
    const int* vertex = (const int*)d_in[3];   // [NE] int32
    const int* edges = (const int*)d_in[4];    // [NE] int32
    float* out = (float*)d_out;                // [NV*256] fp32

    char* ws = (char*)d_ws;
    size_t off = 0;
    #define WS_TAKE(bytes) (ws + off); off += (((size_t)(bytes)) + 15) & ~(size_t)15
    f16* X0 = (f16*)WS_TAKE((size_t)NV * HCC * 2);          // 25.6MB
    f16* Xe = (f16*)WS_TAKE((size_t)NM * HCC * 2);          // 51.2MB
    float* alpha_e = (float*)WS_TAKE((size_t)NM * NHH * 4); // 3.2MB
    // contiguous zeroed region: e_start, v_start (Ce/Cv fully overwritten -> no zero)
    size_t z0 = off;
    int* e_start = (int*)WS_TAKE((size_t)(NM + 1) * 4);
    int* v_start = (int*)WS_TAKE((size_t)(NV + 1) * 4);
    size_t z1 = off;
    int* e_list = (int*)WS_TAKE((size_t)NE * 4);            // 2.4MB
    int* v_list = (int*)WS_TAKE((size_t)NE * 4);            // 2.4MB
    u16* r_e = (u16*)WS_TAKE((size_t)NE * 2);               // 1.2MB rank-in-(chunk,edge)
    u16* r_v = (u16*)WS_TAKE((size_t)NE * 2);               // 1.2MB rank-in-(chunk,vertex)
    u16* Ce = (u16*)WS_TAKE((size_t)NCH * NM * 2);          // 19.2MB chunk-count matrix
    u16* Cv = (u16*)WS_TAKE((size_t)NCH * NV * 2);          // 9.6MB
    int* bsum = (int*)WS_TAKE(64 * 4);                      // 38 used
    #undef WS_TAKE

    hipMemsetAsync(e_start, 0, z1 - z0, stream);

    k_hist_gemm<<<HIST_B + GEMM_B, 256, 0, stream>>>(vertex, edges, r_e, r_v, Ce, Cv,
                                                     X, W, X0);
    k_cscan<<<CSCAN_B, 1024, 0, stream>>>(Ce, Cv, e_start, v_start);
    k_scan_blk<<<SCAN_NB0 + SCAN_NB1, 1024, 0, stream>>>(e_start, v_start, bsum);
    k_scan_add<<<SCAN_NB0 + SCAN_NB1, 1024, 0, stream>>>(e_start, v_start, bsum);
    k_fill2<<<CNT_B, 256, 0, stream>>>(vertex, edges, r_e, r_v, e_start, v_start,
                                       Ce, Cv, e_list, v_list);
    k_egather<<<NM / 4, 256, 0, stream>>>(e_start, e_list, X0, att, Xe, alpha_e);
    k_vgather<<<NV / 4, 256, 0, stream>>>(v_start, v_list, Xe, alpha_e, out);
}

// Round 9
// 324.057 us; speedup vs baseline: 1.0168x; 1.0168x over previous
//
#include <hip/hip_runtime.h>
#include <hip/hip_bf16.h>
#include <math.h>

#define NV 50000
#define NE 600000
#define NM 100000
#define KIN 256
#define HCC 256
#define NHH 8

// chunked LDS histogram geometry (round-7 proven)
#define NCH 32                 // chunks
#define CHUNK 18750            // NE / NCH
#define KRANGE 25000           // keys per LDS pass (u16-packed: 12500 u32 = 50KB)
#define NPASS 6                // passes 0-3: e-side (4x25K=100K), 4-5: v-side (2x25K=50K)
#define HIST_B (NCH * NPASS)   // 192
#define CSCAN_B 74             // ceil((NM/2 + NV/2)/1024)

// parallel scan geometry: 4096 elements per block (1024 threads x int4)
#define SCAN_NB0 25   // ceil((NM+1)/4096)
#define SCAN_NB1 13   // ceil((NV+1)/4096)

#define CNT_B 2344    // ceil(NE/256) fill blocks (divisible by 8 -> remap preserved)
#define GEMM_RG 784   // row-groups launched (782 real + 2 spare for the 8-row remap)
#define GEMM_B (GEMM_RG * 4)

typedef unsigned int u32;
typedef unsigned short u16;
typedef _Float16 f16;
typedef _Float16 v8h __attribute__((ext_vector_type(8)));
typedef _Float16 v4h __attribute__((ext_vector_type(4)));
typedef float v4f __attribute__((ext_vector_type(4)));
typedef float v8f __attribute__((ext_vector_type(8)));

// ---- chunked LDS histogram + rank (atomic-free at global scope) ----
// Standalone (NOT fused with GEMM): round 8 proved the 50KB LDS union cuts GEMM
// occupancy 8->3 blocks/CU and costs more than the fusion saves. Global atomics
// stay eliminated (rounds 3-5: fixed ~12.5 G/s shared pipe regardless of locality).
__global__ __launch_bounds__(256) void k_hist(const int* __restrict__ vertex,
                                              const int* __restrict__ edges,
                                              u16* __restrict__ r_e,
                                              u16* __restrict__ r_v,
                                              u16* __restrict__ Ce,
                                              u16* __restrict__ Cv) {
    __shared__ __align__(16) u32 hist[KRANGE / 2];   // 50KB
    const int bid = blockIdx.x;
    const int t = threadIdx.x;
    const int pass = bid >> 5;            // 0..5
    const int chunk = bid & (NCH - 1);
    const bool eside = pass < 4;
    const int kbase = (eside ? pass : pass - 4) * KRANGE;
    const int* keys = eside ? edges : vertex;
    u16* rout = eside ? r_e : r_v;
    u16* crow = eside ? (Ce + (size_t)chunk * NM) : (Cv + (size_t)chunk * NV);

    uint4* h4 = (uint4*)hist;
    for (int j = t; j < KRANGE / 8; j += 256) h4[j] = make_uint4(0u, 0u, 0u, 0u);
    __syncthreads();

    const int i0 = chunk * CHUNK;
    for (int i = i0 + t; i < i0 + CHUNK; i += 256) {
        int k = keys[i] - kbase;
        if ((u32)k < (u32)KRANGE) {
            int sh = (k & 1) << 4;
            u32 old = atomicAdd(&hist[k >> 1], 1u << sh);
            rout[i] = (u16)(old >> sh);
        }
    }
    __syncthreads();

    uint4* d4 = (uint4*)(crow + kbase);   // 16B-aligned: strides & kbase*2 %16==0
    for (int j = t; j < KRANGE / 8; j += 256) d4[j] = h4[j];
}

// ---- column scan over chunks: C[c][k] -> exclusive prefix over c; totals out ----
// Packed-u32 arithmetic on u16 pairs (no carry: per-key totals <= ~60).
// Writes EVERY e_start/v_start entry except [0] -> memset shrinks to 4B each.
__global__ __launch_bounds__(1024) void k_cscan(u16* __restrict__ Ce,
                                                u16* __restrict__ Cv,
                                                int* __restrict__ e_start,
                                                int* __restrict__ v_start) {
    int tid = blockIdx.x * 1024 + threadIdx.x;
    u32* mat;
    int* outp;
    int col, ncol;
    if (tid < NM / 2)               { mat = (u32*)Ce; outp = e_start; col = tid;          ncol = NM / 2; }
    else if (tid < NM / 2 + NV / 2) { mat = (u32*)Cv; outp = v_start; col = tid - NM / 2; ncol = NV / 2; }
    else return;
    u32 s = 0;
    u32* p = mat + col;
    for (int c = 0; c < NCH; ++c) {
        u32 o = *p;
        *p = s;
        s += o;
        p += ncol;
    }
    outp[2 * col + 1] = (int)(s & 0xffffu);
    outp[2 * col + 2] = (int)(s >> 16);
}

// ---------------- parallel scan pass 1: per-block inclusive scan + block sums ------
__global__ __launch_bounds__(1024) void k_scan_blk(int* __restrict__ a0,
                                                   int* __restrict__ a1,
                                                   int* __restrict__ bsum) {
    const int b = blockIdx.x;
    int* a;
    int n, base;
    if (b < SCAN_NB0) { a = a0; n = NM + 1; base = b * 4096; }
    else              { a = a1; n = NV + 1; base = (b - SCAN_NB0) * 4096; }
    const int t = threadIdx.x;
    const int lane = t & 63, w = t >> 6;
    const int i = base + t * 4;
    int4 v = make_int4(0, 0, 0, 0);
    if (i + 3 < n) v = *(const int4*)(a + i);
    else if (i < n) {
        v.x = a[i];
        if (i + 1 < n) v.y = a[i + 1];
        if (i + 2 < n) v.z = a[i + 2];
    }
    v.y += v.x; v.z += v.y; v.w += v.z;
    int s = v.w;
    #pragma unroll
    for (int d = 1; d < 64; d <<= 1) {
        int x = __shfl_up(s, d, 64);
        if (lane >= d) s += x;
    }
    __shared__ int partials[16];
    __shared__ int woff[16];
    if (lane == 63) partials[w] = s;
    __syncthreads();
    if (t < 16) {
        int p = partials[t];
        int ps = p;
        #pragma unroll
        for (int d = 1; d < 16; d <<= 1) {
            int x = __shfl_up(ps, d, 64);
            if (t >= d) ps += x;
        }
        woff[t] = ps - p;
        if (t == 15) bsum[b] = ps;
    }
    __syncthreads();
    const int add = (s - v.w) + woff[w];
    v.x += add; v.y += add; v.z += add; v.w += add;
    if (i + 3 < n) *(int4*)(a + i) = v;
    else if (i < n) {
        a[i] = v.x;
        if (i + 1 < n) a[i + 1] = v.y;
        if (i + 2 < n) a[i + 2] = v.z;
    }
}

// ---------------- parallel scan pass 2: add block offsets ----------------
__global__ __launch_bounds__(1024) void k_scan_add(int* __restrict__ a0,
                                                   int* __restrict__ a1,
                                                   const int* __restrict__ bsum) {
    const int b = blockIdx.x;
    int* a;
    int n, bs0, blocal;
    if (b < SCAN_NB0) { a = a0; n = NM + 1; bs0 = 0;        blocal = b; }
    else              { a = a1; n = NV + 1; bs0 = SCAN_NB0; blocal = b - SCAN_NB0; }
    const int t = threadIdx.x;
    const int lane = t & 63;
    int x = (lane < blocal) ? bsum[bs0 + lane] : 0;
    #pragma unroll
    for (int d = 1; d < 64; d <<= 1) x += __shfl_xor(x, d, 64);
    const int off = x;
    const int i = blocal * 4096 + t * 4;
    if (i + 3 < n) {
        int4 v = *(const int4*)(a + i);
        v.x += off; v.y += off; v.z += off; v.w += off;
        *(int4*)(a + i) = v;
    } else if (i < n) {
        a[i] += off;
        if (i + 1 < n) a[i + 1] += off;
        if (i + 2 < n) a[i + 2] += off;
    }
}

// ---- fused: merged CSR fill (no LDS) blocks || fp16 MFMA GEMM blocks ----
// The RIGHT fusion partner: fill2 uses zero LDS, so the GEMM keeps its 18.4KB
// -> 8 blocks/CU (round 8's 50KB hist union dropped it to 3 -> regression).
// fill2 (latency/scatter-bound) and GEMM (MFMA-bound) are independent; the
// GEMM's ~35us hides under the scatter pass.
// blocks [0, CNT_B): pos = seg start + chunk offset (cscan) + rank; both scatters.
// blocks [CNT_B, ...): X0 = f16(X @ W); XCD remap g&7==rg&7 (CNT_B%8==0).
__global__ __launch_bounds__(256) void k_gemm_fill2(const int* __restrict__ vertex,
                                                    const int* __restrict__ edges,
                                                    const u16* __restrict__ r_e,
                                                    const u16* __restrict__ r_v,
                                                    const int* __restrict__ e_start,
                                                    const int* __restrict__ v_start,
                                                    const u16* __restrict__ Ce,
                                                    const u16* __restrict__ Cv,
                                                    int* __restrict__ e_list,
                                                    int* __restrict__ v_list,
                                                    const float* __restrict__ X,
                                                    const float* __restrict__ W,
                                                    f16* __restrict__ X0) {
    __shared__ __align__(16) f16 sA[64][72];
    __shared__ __align__(16) f16 sB[64][72];
    const int bid = blockIdx.x;
    const int t = threadIdx.x;
    if (bid < CNT_B) {
        int i = bid * 256 + t;
        if (i < NE) {
            int v = vertex[i], m = edges[i];
            int chunk = i / CHUNK;
            int pe = e_start[m] + (int)Ce[(size_t)chunk * NM + m] + (int)r_e[i];
            e_list[pe] = v;
            int pv = v_start[v] + (int)Cv[(size_t)chunk * NV + v] + (int)r_v[i];
            v_list[pv] = m;
        }
        return;
    }
    const int g = bid - CNT_B;
    const int rg = (g >> 5) * 8 + (g & 7);     // row-group
    const int cg = (g >> 3) & 3;               // column-group
    if (rg >= (NV + 63) / 64) return;
    const int r0 = rg * 64;
    const int c0 = cg * 64;
    const int wave = t >> 6;
    const int lane = t & 63;
    const int quad = lane >> 4;
    const int l16 = lane & 15;
    const int wr = wave & 1;
    const int wc = wave >> 1;

    v4f acc[2][2] = {{{0.f,0.f,0.f,0.f},{0.f,0.f,0.f,0.f}},
                     {{0.f,0.f,0.f,0.f},{0.f,0.f,0.f,0.f}}};

    for (int kc = 0; kc < KIN; kc += 64) {
        __syncthreads();
        #pragma unroll
        for (int i = 0; i < 4; ++i) {
            int lin = i * 256 + t;
            int row = lin >> 4;
            int k = (lin & 15) * 4;
            int gr = r0 + row;
            float4 x = make_float4(0.f, 0.f, 0.f, 0.f);
            if (gr < NV) x = *(const float4*)(X + (size_t)gr * KIN + kc + k);
            v4h hv = { (f16)x.x, (f16)x.y, (f16)x.z, (f16)x.w };
            *(v4h*)&sA[row][k] = hv;
        }
        #pragma unroll
        for (int i = 0; i < 4; ++i) {
            int lin = i * 256 + t;
            int k = lin >> 4;
            int n = (lin & 15) * 4;
            float4 b = *(const float4*)(W + (size_t)(kc + k) * HCC + c0 + n);
            sB[n + 0][k] = (f16)b.x;
            sB[n + 1][k] = (f16)b.y;
            sB[n + 2][k] = (f16)b.z;
            sB[n + 3][k] = (f16)b.w;
        }
        __syncthreads();
        #pragma unroll
        for (int ks = 0; ks < 2; ++ks) {
            const int kb = ks * 32 + quad * 8;
            v8h a[2], b[2];
            #pragma unroll
            for (int rf = 0; rf < 2; ++rf)
                a[rf] = *(const v8h*)&sA[wr * 32 + rf * 16 + l16][kb];
            #pragma unroll
            for (int cf = 0; cf < 2; ++cf)
                b[cf] = *(const v8h*)&sB[wc * 32 + cf * 16 + l16][kb];
            #pragma unroll
            for (int rf = 0; rf < 2; ++rf)
                #pragma unroll
                for (int cf = 0; cf < 2; ++cf)
                    acc[rf][cf] = __builtin_amdgcn_mfma_f32_16x16x32_f16(a[rf], b[cf], acc[rf][cf], 0, 0, 0);
        }
    }
    #pragma unroll
    for (int rf = 0; rf < 2; ++rf)
        #pragma unroll
        for (int cf = 0; cf < 2; ++cf)
            #pragma unroll
            for (int r = 0; r < 4; ++r) {
                int grow = r0 + wr * 32 + rf * 16 + quad * 4 + r;
                if (grow < NV)
                    X0[(size_t)grow * HCC + c0 + wc * 32 + cf * 16 + l16] = (f16)acc[rf][cf][r];
            }
}

// ---------------- per-hyperedge gather: mean of member X0 rows + alpha_e ----------------
// one wave per hyperedge; 16B/lane (v8h): half-wave = even/odd member, lane owns
// 8 channels; halves merged with one shfl_xor(32) per channel at the end.
__global__ __launch_bounds__(256) void k_egather(const int* __restrict__ e_start,
                                                 const int* __restrict__ e_list,
                                                 const f16* __restrict__ X0,
                                                 const float* __restrict__ att,
                                                 f16* __restrict__ Xe,
                                                 float* __restrict__ alpha_e) {
    int m = blockIdx.x * 4 + (threadIdx.x >> 6);
    int lane = threadIdx.x & 63;
    int half = lane >> 5;
    int l32 = lane & 31;
    int c8 = l32 * 8;
    int s0 = e_start[m], s1 = e_start[m + 1];
    v8f acc = {0.f,0.f,0.f,0.f,0.f,0.f,0.f,0.f};
    int i = s0 + half;
    for (; i + 2 < s1; i += 4) {
        int v0 = e_list[i], v1 = e_list[i + 2];
        v8h x0 = *(const v8h*)(X0 + (size_t)v0 * HCC + c8);
        v8h x1 = *(const v8h*)(X0 + (size_t)v1 * HCC + c8);
        #pragma unroll
        for (int j = 0; j < 8; ++j) acc[j] += (float)x0[j] + (float)x1[j];
    }
    if (i < s1) {
        int v0 = e_list[i];
        v8h x0 = *(const v8h*)(X0 + (size_t)v0 * HCC + c8);
        #pragma unroll
        for (int j = 0; j < 8; ++j) acc[j] += (float)x0[j];
    }
    #pragma unroll
    for (int j = 0; j < 8; ++j) acc[j] += __shfl_xor(acc[j], 32, 64);
    float inv = 1.0f / fmaxf((float)(s1 - s0), 1.0f);
    #pragma unroll
    for (int j = 0; j < 8; ++j) acc[j] *= inv;
    if (half == 0) {
        v8h xv;
        #pragma unroll
        for (int j = 0; j < 8; ++j) xv[j] = (f16)acc[j];
        *(v8h*)(Xe + (size_t)m * HCC + c8) = xv;
    }
    float4 a0 = *(const float4*)(att + c8);
    float4 a1 = *(const float4*)(att + c8 + 4);
    float p = acc[0]*a0.x + acc[1]*a0.y + acc[2]*a0.z + acc[3]*a0.w
            + acc[4]*a1.x + acc[5]*a1.y + acc[6]*a1.z + acc[7]*a1.w;
    p += __shfl_xor(p, 1, 64);
    p += __shfl_xor(p, 2, 64);
    if (half == 0 && (l32 & 3) == 0) alpha_e[m * NHH + (l32 >> 2)] = p;
}

// ---------------- per-vertex gather: softmax (no max shift; |alpha|<~2) + GELU ----------
// 16B/lane v8h Xe loads; half-wave = even/odd incident edge; merge via shfl_xor(32).
__global__ __launch_bounds__(256) void k_vgather(const int* __restrict__ v_start,
                                                 const int* __restrict__ v_list,
                                                 const f16* __restrict__ Xe,
                                                 const float* __restrict__ alpha_e,
                                                 float* __restrict__ out) {
    int v = blockIdx.x * 4 + (threadIdx.x >> 6);
    int lane = threadIdx.x & 63;
    int half = lane >> 5;
    int l32 = lane & 31;
    int h = l32 >> 2;
    int c8 = l32 * 8;
    int s0 = v_start[v], s1 = v_start[v + 1];
    v8f acc = {0.f,0.f,0.f,0.f,0.f,0.f,0.f,0.f};
    float se = 0.f;
    int i = s0 + half;
    for (; i + 2 < s1; i += 4) {
        int m0 = v_list[i], m1 = v_list[i + 2];
        float a0 = alpha_e[m0 * NHH + h];
        float a1 = alpha_e[m1 * NHH + h];
        v8h x0 = *(const v8h*)(Xe + (size_t)m0 * HCC + c8);
        v8h x1 = *(const v8h*)(Xe + (size_t)m1 * HCC + c8);
        a0 = (a0 >= 0.f) ? a0 : 0.2f * a0;
        a1 = (a1 >= 0.f) ? a1 : 0.2f * a1;
        float e0 = __expf(a0);
        float e1 = __expf(a1);
        #pragma unroll
        for (int j = 0; j < 8; ++j) acc[j] += e0 * (float)x0[j] + e1 * (float)x1[j];
        se += e0 + e1;
    }
    if (i < s1) {
        int m0 = v_list[i];
        float a0 = alpha_e[m0 * NHH + h];
        v8h x0 = *(const v8h*)(Xe + (size_t)m0 * HCC + c8);
        a0 = (a0 >= 0.f) ? a0 : 0.2f * a0;
        float e0 = __expf(a0);
        #pragma unroll
        for (int j = 0; j < 8; ++j) acc[j] += e0 * (float)x0[j];
        se += e0;
    }
    #pragma unroll
    for (int j = 0; j < 8; ++j) acc[j] += __shfl_xor(acc[j], 32, 64);
    se += __shfl_xor(se, 32, 64);
    if (half) return;
    float inv = 1.0f / (se + 1e-16f);
    float4 o0, o1;
    float xx;
    xx = acc[0] * inv; o0.x = 0.5f * xx * (1.f + erff(xx * 0.70710678118f));
    xx = acc[1] * inv; o0.y = 0.5f * xx * (1.f + erff(xx * 0.70710678118f));
    xx = acc[2] * inv; o0.z = 0.5f * xx * (1.f + erff(xx * 0.70710678118f));
    xx = acc[3] * inv; o0.w = 0.5f * xx * (1.f + erff(xx * 0.70710678118f));
    xx = acc[4] * inv; o1.x = 0.5f * xx * (1.f + erff(xx * 0.70710678118f));
    xx = acc[5] * inv; o1.y = 0.5f * xx * (1.f + erff(xx * 0.70710678118f));
    xx = acc[6] * inv; o1.z = 0.5f * xx * (1.f + erff(xx * 0.70710678118f));
    xx = acc[7] * inv; o1.w = 0.5f * xx * (1.f + erff(xx * 0.70710678118f));
    *(float4*)(out + (size_t)v * HCC + c8) = o0;
    *(float4*)(out + (size_t)v * HCC + c8 + 4) = o1;
}

extern "C" void kernel_launch(void* const* d_in, const int* in_sizes, int n_in,
                              void* d_out, int out_size, void* d_ws, size_t ws_size,
                              hipStream_t stream) {
    const float* X = (const float*)d_in[0];    // [NV, 256] fp32
    const float* W = (const float*)d_in[1];    // [256, 256] fp32
    const float* att = (const float*)d_in[2];  // [256] fp32
    const int* vertex = (const int*)d_in[3];   // [NE] int32
    const int* edges = (const int*)d_in[4];    // [NE] int32
    float* out = (float*)d_out;                // [NV*256] fp32

    char* ws = (char*)d_ws;
    size_t off = 0;
    #define WS_TAKE(bytes) (ws + off); off += (((size_t)(bytes)) + 15) & ~(size_t)15
    f16* X0 = (f16*)WS_TAKE((size_t)NV * HCC * 2);          // 25.6MB
    f16* Xe = (f16*)WS_TAKE((size_t)NM * HCC * 2);          // 51.2MB
    float* alpha_e = (float*)WS_TAKE((size_t)NM * NHH * 4); // 3.2MB
    int* e_start = (int*)WS_TAKE((size_t)(NM + 1) * 4);
    int* v_start = (int*)WS_TAKE((size_t)(NV + 1) * 4);
    int* e_list = (int*)WS_TAKE((size_t)NE * 4);            // 2.4MB
    int* v_list = (int*)WS_TAKE((size_t)NE * 4);            // 2.4MB
    u16* r_e = (u16*)WS_TAKE((size_t)NE * 2);               // 1.2MB rank-in-(chunk,edge)
    u16* r_v = (u16*)WS_TAKE((size_t)NE * 2);               // 1.2MB rank-in-(chunk,vertex)
    u16* Ce = (u16*)WS_TAKE((size_t)NCH * NM * 2);          // 6.4MB chunk-count matrix
    u16* Cv = (u16*)WS_TAKE((size_t)NCH * NV * 2);          // 3.2MB
    int* bsum = (int*)WS_TAKE(64 * 4);                      // 38 used
    #undef WS_TAKE

    // cscan overwrites e_start[1..NM] / v_start[1..NV]; only index 0 needs zeroing
    hipMemsetAsync(e_start, 0, 4, stream);
    hipMemsetAsync(v_start, 0, 4, stream);

    k_hist<<<HIST_B, 256, 0, stream>>>(vertex, edges, r_e, r_v, Ce, Cv);
    k_cscan<<<CSCAN_B, 1024, 0, stream>>>(Ce, Cv, e_start, v_start);
    k_scan_blk<<<SCAN_NB0 + SCAN_NB1, 1024, 0, stream>>>(e_start, v_start, bsum);
    k_scan_add<<<SCAN_NB0 + SCAN_NB1, 1024, 0, stream>>>(e_start, v_start, bsum);
    k_gemm_fill2<<<CNT_B + GEMM_B, 256, 0, stream>>>(vertex, edges, r_e, r_v,
                                                     e_start, v_start, Ce, Cv,
                                                     e_list, v_list, X, W, X0);
    k_egather<<<NM / 4, 256, 0, stream>>>(e_start, e_list, X0, att, Xe, alpha_e);
    k_vgather<<<NV / 4, 256, 0, stream>>>(v_start, v_list, Xe, alpha_e, out);
}